// Round 6
// baseline (1302.350 us; speedup 1.0000x reference)
//
#include <hip/hip_runtime.h>
#include <math.h>

// SingleGAP: per-point tiny MLPs + GLOBAL softmax over N (axis 0, faithful bug),
// then attention-weighted sum. out0 = [N][16] x_attn, out1 = [N][160] h2 (flat,
// [F][K] order per point == x2v raw reshape).
//
// K1: quad-per-point, software-pipelined (prefetch depth 1). Lane q of a quad
//     loads only its quarter of the xknn row ([40q,40q+40), 10 float4) and owns
//     features f=4q..4q+3. h2 sweep uses quad_perm DPP broadcasts; logits use
//     u = W1^T Wf (so a2/a1 come straight from x-data, no h1 pass).
// K2: reduce per-block (m,s) -> global (m,s) per k-slot.
// K3: quad-per-point weighted sum: out0 = softmax(logits) @ x2v.

__device__ __forceinline__ void comb(float& m, float& s, float om, float os) {
  float M = fmaxf(m, om);
  if (M == -INFINITY) return;  // both empty
  s = s * __expf(m - M) + os * __expf(om - M);
  m = M;
}

// Broadcast the value of quad-lane SRC to all 4 lanes of each quad.
template <int CTRL>
__device__ __forceinline__ float qb(float v) {
  return __int_as_float(__builtin_amdgcn_update_dpp(
      0, __float_as_int(v), CTRL, 0xf, 0xf, true));
}

__device__ __forceinline__ float f4e(const float4& v, int e) {
  // e is always a compile-time constant under full unroll
  return (e == 0) ? v.x : (e == 1) ? v.y : (e == 2) ? v.z : v.w;
}

__global__ __launch_bounds__(256, 2) void gap_k1(
    const float* __restrict__ xknn, const float* __restrict__ x,
    const float* __restrict__ Wf, const float* __restrict__ bf,
    const float* __restrict__ W1, const float* __restrict__ b1p,
    float* __restrict__ out, float* __restrict__ partials, int n) {
  __shared__ float s_red[4][16][2];

  const int tid = threadIdx.x;
  const int q = tid & 3;          // quad lane: owns f = 4q..4q+3 AND quarter q
  const int lane = tid & 63;
  const int wave = tid >> 6;

  // per-lane weights: Wf rows 4q..4q+3, bf[4q..4q+3]
  float wfq[4][16], bfq[4];
  float w1q[4];
#pragma unroll
  for (int fp = 0; fp < 4; ++fp) {
    const float* wr = Wf + (size_t)(4 * q + fp) * 16;
#pragma unroll
    for (int dq = 0; dq < 4; ++dq) {
      float4 v = *(const float4*)(wr + dq * 4);
      wfq[fp][dq * 4 + 0] = v.x;
      wfq[fp][dq * 4 + 1] = v.y;
      wfq[fp][dq * 4 + 2] = v.z;
      wfq[fp][dq * 4 + 3] = v.w;
    }
    w1q[fp] = W1[4 * q + fp];
    bfq[fp] = bf[4 * q + fp];
  }
  const float b1v = b1p[0];

  // u[d] = sum_f W1[f] Wf[f][d] via quad butterfly (each lane has 4 f-rows)
  float ufull[16];
#pragma unroll
  for (int d = 0; d < 16; ++d) {
    float t = w1q[0] * wfq[0][d];
    t = fmaf(w1q[1], wfq[1][d], t);
    t = fmaf(w1q[2], wfq[2][d], t);
    t = fmaf(w1q[3], wfq[3][d], t);
    ufull[d] = t;
  }
#pragma unroll
  for (int d = 0; d < 16; ++d) ufull[d] += __shfl_xor(ufull[d], 1);
#pragma unroll
  for (int d = 0; d < 16; ++d) ufull[d] += __shfl_xor(ufull[d], 2);
  // own-quarter u (compile-time index select chain)
  float u4[4];
#pragma unroll
  for (int i = 0; i < 4; ++i) {
    float v = ufull[i];
    v = (q == 1) ? ufull[4 + i] : v;
    v = (q == 2) ? ufull[8 + i] : v;
    v = (q == 3) ? ufull[12 + i] : v;
    u4[i] = v;
  }
  // sigma_b = sum_f W1[f] bf[f]
  float sb = w1q[0] * bfq[0];
  sb = fmaf(w1q[1], bfq[1], sb);
  sb = fmaf(w1q[2], bfq[2], sb);
  sb = fmaf(w1q[3], bfq[3], sb);
  sb += __shfl_xor(sb, 1);
  sb += __shfl_xor(sb, 2);
  const float addK = 2.0f * (sb + b1v);  // logit = pa[k] + a1u + addK

  // online softmax state for owned k = 4q+j (invalid slots stay empty)
  float rm[4] = {-INFINITY, -INFINITY, -INFINITY, -INFINITY};
  float rs[4] = {0.f, 0.f, 0.f, 0.f};

  float* out0 = out;                       // [n][16]  (logits now, x_attn later)
  float* out1 = out + (size_t)n * 16;      // [n][160] h2 flat ([F][K] per point)

  const long quad0 = (long)blockIdx.x * 64 + (tid >> 2);
  const long qstride = (long)gridDim.x * 64;

  // prologue: load cur for first point
  float4 cur[10], xc;
  {
    const long p0 = (quad0 < n) ? quad0 : 0;
    const float* rowq = xknn + (size_t)p0 * 160 + 40 * q;
#pragma unroll
    for (int j = 0; j < 10; ++j) cur[j] = *(const float4*)(rowq + 4 * j);
    xc = *(const float4*)(x + (size_t)p0 * 16 + 4 * q);
  }

  for (long pt = quad0; pt < n; pt += qstride) {
    // ---- prefetch next iteration's data (stays in flight across compute) ----
    const long ptn = pt + qstride;
    const long ptl = (ptn < n) ? ptn : pt;
    float4 nxt[10], xn;
    {
      const float* rowq = xknn + (size_t)ptl * 160 + 40 * q;
#pragma unroll
      for (int j = 0; j < 10; ++j) nxt[j] = *(const float4*)(rowq + 4 * j);
      xn = *(const float4*)(x + (size_t)ptl * 16 + 4 * q);
    }

    // ---- pa[k] = sum_{d in own quarter} u[d] * x2[d][k]  (own data only) ----
    float pa[10];
#pragma unroll
    for (int k = 0; k < 10; ++k) pa[k] = 0.f;
#pragma unroll
    for (int rr = 0; rr < 40; ++rr) {
      const int dl = rr / 10, k = rr - dl * 10;
      pa[k] = fmaf(u4[dl], f4e(cur[rr / 4], rr % 4), pa[k]);
    }
    // a1 part: sum_{d in own quarter} u[d] * x[d]
    float a1u = u4[0] * xc.x;
    a1u = fmaf(u4[1], xc.y, a1u);
    a1u = fmaf(u4[2], xc.z, a1u);
    a1u = fmaf(u4[3], xc.w, a1u);
    // quad butterflies -> full sums on all 4 lanes
#pragma unroll
    for (int k = 0; k < 10; ++k) pa[k] += __shfl_xor(pa[k], 1);
#pragma unroll
    for (int k = 0; k < 10; ++k) pa[k] += __shfl_xor(pa[k], 2);
    a1u += __shfl_xor(a1u, 1);
    a1u += __shfl_xor(a1u, 2);
    const float addc = a1u + addK;

    // ---- h2 sweep: acc[fp][k] = bf + sum_d Wf[fp][d] x2[d][k] (DPP bcast) ----
    float acc[4][10];
#pragma unroll
    for (int fp = 0; fp < 4; ++fp)
#pragma unroll
      for (int k = 0; k < 10; ++k) acc[fp][k] = bfq[fp];
#pragma unroll
    for (int src = 0; src < 4; ++src) {
#pragma unroll
      for (int rr = 0; rr < 40; ++rr) {
        const int r = src * 40 + rr;
        const int d = r / 10, k = r - d * 10;
        const float xe = f4e(cur[rr / 4], rr % 4);
        const float xv = (src == 0)   ? qb<0x00>(xe)
                         : (src == 1) ? qb<0x55>(xe)
                         : (src == 2) ? qb<0xAA>(xe)
                                      : qb<0xFF>(xe);
        acc[0][k] = fmaf(wfq[0][d], xv, acc[0][k]);
        acc[1][k] = fmaf(wfq[1][d], xv, acc[1][k]);
        acc[2][k] = fmaf(wfq[2][d], xv, acc[2][k]);
        acc[3][k] = fmaf(wfq[3][d], xv, acc[3][k]);
      }
    }

    // ---- logits: lane q takes k = 4q..4q+3 (cndmask chain) ----
    float lj[4];
#pragma unroll
    for (int j = 0; j < 4; ++j) {
      const int k = 4 * q + j;  // runtime q
      float v = 0.f;
#pragma unroll
      for (int kk = 0; kk < 10; ++kk) v = (kk == k) ? (pa[kk] + addc) : v;
      lj[j] = v;
      if (k < 10) comb(rm[j], rs[j], v, 1.0f);
    }
    *(float4*)(out0 + (size_t)pt * 16 + 4 * q) =
        make_float4(lj[0], lj[1], lj[2], lj[3]);

    // ---- h2 -> out1 flat [F][K]: lane q's own contiguous quarter ----
    float* o1 = out1 + (size_t)pt * 160 + 40 * q;
#pragma unroll
    for (int i = 0; i < 10; ++i) {
      const int j0 = 4 * i, j1 = 4 * i + 1, j2 = 4 * i + 2, j3 = 4 * i + 3;
      *(float4*)(o1 + 4 * i) =
          make_float4(acc[j0 / 10][j0 % 10], acc[j1 / 10][j1 % 10],
                      acc[j2 / 10][j2 % 10], acc[j3 / 10][j3 % 10]);
    }

    // ---- rotate pipeline ----
#pragma unroll
    for (int j = 0; j < 10; ++j) cur[j] = nxt[j];
    xc = xn;
  }

  // reduce (m,s) across the wave's 16 quads (lanes differing in bits 2..5)
#pragma unroll
  for (int mask = 4; mask < 64; mask <<= 1) {
#pragma unroll
    for (int j = 0; j < 4; ++j) {
      float om = __shfl_xor(rm[j], mask);
      float os = __shfl_xor(rs[j], mask);
      comb(rm[j], rs[j], om, os);
    }
  }
  if (lane < 4) {  // lane == q-class representative; slot index = k = 4*lane+j
#pragma unroll
    for (int j = 0; j < 4; ++j) {
      s_red[wave][lane * 4 + j][0] = rm[j];
      s_red[wave][lane * 4 + j][1] = rs[j];
    }
  }
  __syncthreads();
  if (tid < 10) {
    float m = s_red[0][tid][0], s = s_red[0][tid][1];
    comb(m, s, s_red[1][tid][0], s_red[1][tid][1]);
    comb(m, s, s_red[2][tid][0], s_red[2][tid][1]);
    comb(m, s, s_red[3][tid][0], s_red[3][tid][1]);
    partials[(size_t)blockIdx.x * 20 + tid * 2 + 0] = m;
    partials[(size_t)blockIdx.x * 20 + tid * 2 + 1] = s;
  }
}

__global__ __launch_bounds__(256) void gap_k2(const float* __restrict__ part,
                                              int nb, float* __restrict__ fin) {
  const int k = blockIdx.x;   // one block per k-slot
  const int tid = threadIdx.x;
  float m = -INFINITY, s = 0.f;
  for (int i = tid; i < nb; i += 256)
    comb(m, s, part[(size_t)i * 20 + k * 2], part[(size_t)i * 20 + k * 2 + 1]);
#pragma unroll
  for (int mask = 1; mask < 64; mask <<= 1) {
    float om = __shfl_xor(m, mask, 64);
    float os = __shfl_xor(s, mask, 64);
    comb(m, s, om, os);
  }
  __shared__ float sm[4][2];
  const int wave = tid >> 6, lane = tid & 63;
  if (lane == 0) { sm[wave][0] = m; sm[wave][1] = s; }
  __syncthreads();
  if (tid == 0) {
    for (int w = 1; w < 4; ++w) comb(m, s, sm[w][0], sm[w][1]);
    fin[k * 2 + 0] = m;
    fin[k * 2 + 1] = s;
  }
}

// K3: 4 lanes per point; lane (p,q) accumulates features f = 4q..4q+3.
// Reads out1 flat at offset k*16+f == x2v[k][f] (raw-reshape identity).
__global__ __launch_bounds__(256) void gap_k3(const float* __restrict__ fin,
                                              float* __restrict__ out, int n) {
  __shared__ float s_fin[20];
  if (threadIdx.x < 20) s_fin[threadIdx.x] = fin[threadIdx.x];
  __syncthreads();
  float mk[10], rsk[10];
#pragma unroll
  for (int k = 0; k < 10; ++k) {
    mk[k] = s_fin[2 * k];
    rsk[k] = 1.0f / s_fin[2 * k + 1];
  }
  float* out0 = out;
  const float* out1 = out + (size_t)n * 16;
  const int q = threadIdx.x & 3;
  const int pl = threadIdx.x >> 2;           // 64 points per block pass
  for (long i = (long)blockIdx.x * 64 + pl; i < n; i += (long)gridDim.x * 64) {
    float* lrow = out0 + i * 16;
    // all 4 lanes of the quad read the same 64B logit line (L1 broadcast)
    float4 la = *(const float4*)(lrow);
    float4 lb = *(const float4*)(lrow + 4);
    float2 lc = *(const float2*)(lrow + 8);
    float l[10] = {la.x, la.y, la.z, la.w, lb.x, lb.y, lb.z, lb.w, lc.x, lc.y};
    float w[10];
#pragma unroll
    for (int k = 0; k < 10; ++k) w[k] = __expf(l[k] - mk[k]) * rsk[k];
    const float* vrow = out1 + i * 160 + q * 4;
    float4 acc = make_float4(0.f, 0.f, 0.f, 0.f);
#pragma unroll
    for (int k = 0; k < 10; ++k) {
      float4 v = *(const float4*)(vrow + k * 16);
      float wk = w[k];
      acc.x = fmaf(wk, v.x, acc.x);
      acc.y = fmaf(wk, v.y, acc.y);
      acc.z = fmaf(wk, v.z, acc.z);
      acc.w = fmaf(wk, v.w, acc.w);
    }
    // store after all reads (wave-lockstep => no RAW hazard on the logit line)
    *(float4*)(lrow + q * 4) = acc;
  }
}

extern "C" void kernel_launch(void* const* d_in, const int* in_sizes, int n_in,
                              void* d_out, int out_size, void* d_ws, size_t ws_size,
                              hipStream_t stream) {
  const float* xknn = (const float*)d_in[0];
  const float* x    = (const float*)d_in[1];
  const float* Wf   = (const float*)d_in[2];
  const float* bf   = (const float*)d_in[3];
  const float* W1   = (const float*)d_in[4];
  const float* b1   = (const float*)d_in[5];
  float* out = (float*)d_out;
  const int n = in_sizes[1] / 16;  // x is [N][16]

  const int G1 = 1024;
  float* partials = (float*)d_ws;                 // [G1][10][2]
  float* finals = partials + (size_t)G1 * 20;     // [10][2]

  gap_k1<<<G1, 256, 0, stream>>>(xknn, x, Wf, bf, W1, b1, out, partials, n);
  gap_k2<<<10, 256, 0, stream>>>(partials, G1, finals);
  gap_k3<<<2048, 256, 0, stream>>>(finals, out, n);
}

// Round 7
// 747.123 us; speedup vs baseline: 1.7432x; 1.7432x over previous
//
#include <hip/hip_runtime.h>
#include <math.h>

// SingleGAP: per-point tiny MLPs + GLOBAL softmax over N (axis 0, faithful bug),
// then attention-weighted sum. out0 = [N][16] x_attn, out1 = [N][160] h2 (flat,
// [F][K] order per point == x2v raw reshape).
//
// K1: double-buffered LDS tile staging (32 points = 20KB/buffer, reg-staged
//     global->LDS with XOR bank swizzle), octet-per-point compute: lane o of a
//     point's 8 lanes owns f={2o,2o+1}; each lane reads the full 640B row from
//     LDS (octet-broadcast, conflict-free via swizzle) -> acc/pa fully local.
//     Writes h2 -> out1, logits -> out0 (stash; K3 overwrites), (m,s) partials.
// K2: reduce per-block (m,s) -> global (m,s) per k-slot.
// K3: quad-per-point weighted sum: out0 = softmax(logits) @ x2v.

#define TILE_PTS 32
#define TILE_F (TILE_PTS * 160)   // floats per tile buffer (5120 = 20KB)

__device__ __forceinline__ void comb(float& m, float& s, float om, float os) {
  float M = fmaxf(m, om);
  if (M == -INFINITY) return;  // both empty
  s = s * __expf(m - M) + os * __expf(om - M);
  m = M;
}

__global__ __launch_bounds__(256) void gap_k1(
    const float* __restrict__ xknn, const float* __restrict__ x,
    const float* __restrict__ Wf, const float* __restrict__ bf,
    const float* __restrict__ W1, const float* __restrict__ b1p,
    float* __restrict__ out, float* __restrict__ partials, int n) {
  __shared__ float smem[2][TILE_F];     // 2 x 20KB staged xknn tiles
  __shared__ float s_red[4][16][2];

  const int tid = threadIdx.x;
  const int o = tid & 7;        // octet lane: owns f = {2o, 2o+1}
  const int p = tid >> 3;       // point-in-tile 0..31
  const int lane = tid & 63;
  const int wave = tid >> 6;
  const int sw = (p & 7) << 4;  // LDS byte-swizzle for this row (bits 4-6)

  // per-lane weights: Wf rows {2o,2o+1}, W1/bf slices
  float wfo[2][16], w1o[2], bfo[2];
#pragma unroll
  for (int fp = 0; fp < 2; ++fp) {
    const float* wr = Wf + (size_t)(2 * o + fp) * 16;
#pragma unroll
    for (int dq = 0; dq < 4; ++dq) {
      float4 v = *(const float4*)(wr + dq * 4);
      wfo[fp][dq * 4 + 0] = v.x;
      wfo[fp][dq * 4 + 1] = v.y;
      wfo[fp][dq * 4 + 2] = v.z;
      wfo[fp][dq * 4 + 3] = v.w;
    }
    w1o[fp] = W1[2 * o + fp];
    bfo[fp] = bf[2 * o + fp];
  }
  const float b1v = b1p[0];

  // ufull[d] = sum_f W1[f]*Wf[f][d]  (octet butterfly: f-coverage = all 16)
  float ufull[16];
#pragma unroll
  for (int d = 0; d < 16; ++d)
    ufull[d] = fmaf(w1o[1], wfo[1][d], w1o[0] * wfo[0][d]);
#pragma unroll
  for (int mk = 1; mk < 8; mk <<= 1)
#pragma unroll
    for (int d = 0; d < 16; ++d) ufull[d] += __shfl_xor(ufull[d], mk);
  float sb = fmaf(w1o[1], bfo[1], w1o[0] * bfo[0]);
  sb += __shfl_xor(sb, 1);
  sb += __shfl_xor(sb, 2);
  sb += __shfl_xor(sb, 4);
  const float addK = 2.0f * (sb + b1v);  // logit = pa[k] + a1u + addK
  // u2 = {u[2o], u[2o+1]} (compile-time select chain over runtime o)
  float u2[2];
#pragma unroll
  for (int j = 0; j < 2; ++j) {
    float v = ufull[j];
#pragma unroll
    for (int oo = 1; oo < 8; ++oo) v = (o == oo) ? ufull[2 * oo + j] : v;
    u2[j] = v;
  }

  // online softmax state for owned k = {2o, 2o+1} (valid for o<5)
  float rm[2] = {-INFINITY, -INFINITY}, rs[2] = {0.f, 0.f};

  float* out0 = out;                       // [n][16]  (logits now, x_attn later)
  float* out1 = out + (size_t)n * 16;      // [n][160] h2 flat ([F][K] per point)

  const long nt = ((long)n + TILE_PTS - 1) / TILE_PTS;
  const long G = gridDim.x;
  long t = (long)blockIdx.x;
  int cur = 0;

  // stage regs: thread stages its OWN point-row chunks j = o+8c (5 x 16B)
  float4 st[5];

  auto STAGE_LOAD = [&](long tt) {
    long pt = tt * TILE_PTS + p;
    const float* row = xknn + ((pt < n) ? (size_t)pt * 160 : (size_t)0);
#pragma unroll
    for (int c = 0; c < 5; ++c) st[c] = *(const float4*)(row + (o + 8 * c) * 4);
  };
  auto STAGE_WRITE = [&](int buf) {
    char* rowb = (char*)&smem[buf][p * 160];
#pragma unroll
    for (int c = 0; c < 5; ++c)
      *(float4*)(rowb + (((o + 8 * c) * 16) ^ sw)) = st[c];
  };

  // prologue: stage first tile
  STAGE_LOAD(t);
  STAGE_WRITE(0);

  for (; t < nt; t += G) {
    const long tn = t + G;
    const bool more = (tn < nt);
    __syncthreads();                 // buf[cur] staged & visible; readers synced
    if (more) STAGE_LOAD(tn);        // fire-and-forget over the compute below

    const long pt = t * TILE_PTS + p;
    // center-point slice (only 2 floats needed thanks to u-trick butterfly)
    float2 xc = make_float2(0.f, 0.f);
    if (pt < n) xc = *(const float2*)(x + (size_t)pt * 16 + 2 * o);

    // full-row sweep from LDS: acc (own 2 f-rows) + pa (u-weighted), local
    const char* rowb = (const char*)&smem[cur][p * 160];
    float acc0[10], acc1[10], pa[10];
#pragma unroll
    for (int k = 0; k < 10; ++k) {
      acc0[k] = bfo[0];
      acc1[k] = bfo[1];
      pa[k] = 0.f;
    }
#pragma unroll
    for (int j = 0; j < 40; ++j) {
      float4 v = *(const float4*)(rowb + ((j * 16) ^ sw));
#pragma unroll
      for (int e = 0; e < 4; ++e) {
        const int r = j * 4 + e, d = r / 10, k = r - d * 10;
        const float xe = (e == 0) ? v.x : (e == 1) ? v.y : (e == 2) ? v.z : v.w;
        acc0[k] = fmaf(wfo[0][d], xe, acc0[k]);
        acc1[k] = fmaf(wfo[1][d], xe, acc1[k]);
        pa[k] = fmaf(ufull[d], xe, pa[k]);
      }
    }

    // a1 = sum_d u[d] x[d] (octet butterfly over 2-float partials)
    float a1p = fmaf(u2[1], xc.y, u2[0] * xc.x);
    a1p += __shfl_xor(a1p, 1);
    a1p += __shfl_xor(a1p, 2);
    a1p += __shfl_xor(a1p, 4);
    const float addc = a1p + addK;

    // logits k = {2o, 2o+1} (cndmask chains; no runtime array index)
    float lj0 = 0.f, lj1 = 0.f;
#pragma unroll
    for (int kk = 0; kk < 10; ++kk) {
      lj0 = (kk == 2 * o) ? (pa[kk] + addc) : lj0;
      lj1 = (kk == 2 * o + 1) ? (pa[kk] + addc) : lj1;
    }

    if (pt < n) {
      *(float2*)(out0 + (size_t)pt * 16 + 2 * o) = make_float2(lj0, lj1);
      if (o < 5) {
        comb(rm[0], rs[0], lj0, 1.0f);
        comb(rm[1], rs[1], lj1, 1.0f);
      }
      // h2 -> out1 flat [F][K]: lane o's region [20o, 20o+20), 80B contiguous
      float* o1 = out1 + (size_t)pt * 160 + 20 * o;
      *(float4*)(o1 + 0) = make_float4(acc0[0], acc0[1], acc0[2], acc0[3]);
      *(float4*)(o1 + 4) = make_float4(acc0[4], acc0[5], acc0[6], acc0[7]);
      *(float4*)(o1 + 8) = make_float4(acc0[8], acc0[9], acc1[0], acc1[1]);
      *(float4*)(o1 + 12) = make_float4(acc1[2], acc1[3], acc1[4], acc1[5]);
      *(float4*)(o1 + 16) = make_float4(acc1[6], acc1[7], acc1[8], acc1[9]);
    }

    if (more) STAGE_WRITE(cur ^ 1);  // land next tile just before its barrier
    cur ^= 1;
  }

  // (m,s) reduce across the wave's 8 points (lane bits 3..5), then block
#pragma unroll
  for (int mk = 8; mk < 64; mk <<= 1) {
#pragma unroll
    for (int j = 0; j < 2; ++j) {
      float om = __shfl_xor(rm[j], mk);
      float os = __shfl_xor(rs[j], mk);
      comb(rm[j], rs[j], om, os);
    }
  }
  if (lane < 5) {
#pragma unroll
    for (int j = 0; j < 2; ++j) {
      s_red[wave][2 * lane + j][0] = rm[j];
      s_red[wave][2 * lane + j][1] = rs[j];
    }
  }
  __syncthreads();
  if (tid < 10) {
    float m = s_red[0][tid][0], s = s_red[0][tid][1];
    comb(m, s, s_red[1][tid][0], s_red[1][tid][1]);
    comb(m, s, s_red[2][tid][0], s_red[2][tid][1]);
    comb(m, s, s_red[3][tid][0], s_red[3][tid][1]);
    partials[(size_t)blockIdx.x * 20 + tid * 2 + 0] = m;
    partials[(size_t)blockIdx.x * 20 + tid * 2 + 1] = s;
  }
}

__global__ __launch_bounds__(256) void gap_k2(const float* __restrict__ part,
                                              int nb, float* __restrict__ fin) {
  const int k = blockIdx.x;   // one block per k-slot
  const int tid = threadIdx.x;
  float m = -INFINITY, s = 0.f;
  for (int i = tid; i < nb; i += 256)
    comb(m, s, part[(size_t)i * 20 + k * 2], part[(size_t)i * 20 + k * 2 + 1]);
#pragma unroll
  for (int mask = 1; mask < 64; mask <<= 1) {
    float om = __shfl_xor(m, mask, 64);
    float os = __shfl_xor(s, mask, 64);
    comb(m, s, om, os);
  }
  __shared__ float sm[4][2];
  const int wave = tid >> 6, lane = tid & 63;
  if (lane == 0) { sm[wave][0] = m; sm[wave][1] = s; }
  __syncthreads();
  if (tid == 0) {
    for (int w = 1; w < 4; ++w) comb(m, s, sm[w][0], sm[w][1]);
    fin[k * 2 + 0] = m;
    fin[k * 2 + 1] = s;
  }
}

// K3: 4 lanes per point; lane (p,q) accumulates features f = 4q..4q+3.
// Reads out1 flat at offset k*16+f == x2v[k][f] (raw-reshape identity).
__global__ __launch_bounds__(256) void gap_k3(const float* __restrict__ fin,
                                              float* __restrict__ out, int n) {
  __shared__ float s_fin[20];
  if (threadIdx.x < 20) s_fin[threadIdx.x] = fin[threadIdx.x];
  __syncthreads();
  float mk[10], rsk[10];
#pragma unroll
  for (int k = 0; k < 10; ++k) {
    mk[k] = s_fin[2 * k];
    rsk[k] = 1.0f / s_fin[2 * k + 1];
  }
  float* out0 = out;
  const float* out1 = out + (size_t)n * 16;
  const int q = threadIdx.x & 3;
  const int pl = threadIdx.x >> 2;           // 64 points per block pass
  for (long i = (long)blockIdx.x * 64 + pl; i < n; i += (long)gridDim.x * 64) {
    float* lrow = out0 + i * 16;
    // all 4 lanes of the quad read the same 64B logit line (L1 broadcast)
    float4 la = *(const float4*)(lrow);
    float4 lb = *(const float4*)(lrow + 4);
    float2 lc = *(const float2*)(lrow + 8);
    float l[10] = {la.x, la.y, la.z, la.w, lb.x, lb.y, lb.z, lb.w, lc.x, lc.y};
    float w[10];
#pragma unroll
    for (int k = 0; k < 10; ++k) w[k] = __expf(l[k] - mk[k]) * rsk[k];
    const float* vrow = out1 + i * 160 + q * 4;
    float4 acc = make_float4(0.f, 0.f, 0.f, 0.f);
#pragma unroll
    for (int k = 0; k < 10; ++k) {
      float4 v = *(const float4*)(vrow + k * 16);
      float wk = w[k];
      acc.x = fmaf(wk, v.x, acc.x);
      acc.y = fmaf(wk, v.y, acc.y);
      acc.z = fmaf(wk, v.z, acc.z);
      acc.w = fmaf(wk, v.w, acc.w);
    }
    // store after all reads (wave-lockstep => no RAW hazard on the logit line)
    *(float4*)(lrow + q * 4) = acc;
  }
}

extern "C" void kernel_launch(void* const* d_in, const int* in_sizes, int n_in,
                              void* d_out, int out_size, void* d_ws, size_t ws_size,
                              hipStream_t stream) {
  const float* xknn = (const float*)d_in[0];
  const float* x    = (const float*)d_in[1];
  const float* Wf   = (const float*)d_in[2];
  const float* bf   = (const float*)d_in[3];
  const float* W1   = (const float*)d_in[4];
  const float* b1   = (const float*)d_in[5];
  float* out = (float*)d_out;
  const int n = in_sizes[1] / 16;  // x is [N][16]

  const int G1 = 1536;
  float* partials = (float*)d_ws;                 // [G1][10][2]
  float* finals = partials + (size_t)G1 * 20;     // [10][2]

  gap_k1<<<G1, 256, 0, stream>>>(xknn, x, Wf, bf, W1, b1, out, partials, n);
  gap_k2<<<10, 256, 0, stream>>>(partials, G1, finals);
  gap_k3<<<2048, 256, 0, stream>>>(finals, out, n);
}